// Round 5
// baseline (203.813 us; speedup 1.0000x reference)
//
#include <hip/hip_runtime.h>
#include <hip/hip_bf16.h>

#define NEG_SLOPE 0.2f

__device__ __forceinline__ float lrelu(float x) {
    return x > 0.f ? x : NEG_SLOPE * x;
}

// ================= CSR build =================
__global__ void zero_cnt_kernel(int* __restrict__ cnt, int n) {
    int i = blockIdx.x * blockDim.x + threadIdx.x;
    if (i < n) cnt[i] = 0;
}

// A) per-block bucket histogram (LDS) + fused per-node count (global atomics)
__global__ void bincount_kernel(const int* __restrict__ ei, int E, int n, int CH,
                                int* __restrict__ bh, int* __restrict__ cnt,
                                int nbuck, int nblk) {
    __shared__ int lhist[128];
    for (int i = threadIdx.x; i < nbuck; i += blockDim.x) lhist[i] = 0;
    __syncthreads();
    int beg = blockIdx.x * CH;
    int end = min(beg + CH, E + n);
    for (int e = beg + threadIdx.x; e < end; e += blockDim.x) {
        int d = (e < E) ? ei[E + e] : (e - E);
        atomicAdd(&lhist[d >> 9], 1);
        atomicAdd(&cnt[d], 1);
    }
    __syncthreads();
    for (int i = threadIdx.x; i < nbuck; i += blockDim.x)
        bh[i * nblk + blockIdx.x] = lhist[i];
}

// B) single-block exclusive scan of bh[nbuck*nblk] (bucket-major) + bucket bases bb
__global__ void bhscan_kernel(int* __restrict__ bh, int* __restrict__ bb,
                              int total, int nbuck, int nblk) {
    __shared__ int wpart[16];
    __shared__ int s_carry;
    int t = threadIdx.x;
    int lane = t & 63, wid = t >> 6;
    if (t == 0) s_carry = 0;
    __syncthreads();
    int rounds = (total + 1023) / 1024;
    for (int r = 0; r < rounds; ++r) {
        int idx = r * 1024 + t;
        int v = (idx < total) ? bh[idx] : 0;
        int orig = v;
#pragma unroll
        for (int off = 1; off < 64; off <<= 1) {
            int u = __shfl_up(v, off, 64);
            if (lane >= off) v += u;
        }
        if (lane == 63) wpart[wid] = v;
        __syncthreads();
        if (wid == 0) {
            int wv = (lane < 16) ? wpart[lane] : 0;
#pragma unroll
            for (int off = 1; off < 16; off <<= 1) {
                int u = __shfl_up(wv, off, 64);
                if (lane >= off) wv += u;
            }
            if (lane < 16) wpart[lane] = wv;
        }
        __syncthreads();
        int woff = (wid == 0) ? 0 : wpart[wid - 1];
        int excl = s_carry + woff + v - orig;
        if (idx < total) bh[idx] = excl;
        __syncthreads();
        if (t == 1023) s_carry += wpart[15];
        __syncthreads();
    }
    for (int b = t; b < nbuck; b += 1024) bb[b] = bh[(size_t)b * nblk];
    if (t == 0) bb[nbuck] = s_carry;
}

// C) bucket-grouped scatter of packed (dst_local<<23 | src); block-local regions
__global__ void binscatter_kernel(const int* __restrict__ ei, int E, int n, int CH,
                                  const int* __restrict__ bh, unsigned int* __restrict__ pk,
                                  int nbuck, int nblk) {
    __shared__ int lcur[128];
    for (int i = threadIdx.x; i < nbuck; i += blockDim.x) lcur[i] = bh[i * nblk + blockIdx.x];
    __syncthreads();
    int beg = blockIdx.x * CH;
    int end = min(beg + CH, E + n);
    for (int e = beg + threadIdx.x; e < end; e += blockDim.x) {
        int s, d;
        if (e < E) { s = ei[e]; d = ei[E + e]; } else { s = d = e - E; }
        int slot = atomicAdd(&lcur[d >> 9], 1);
        pk[slot] = ((unsigned int)(d & 511) << 23) | (unsigned int)s;
    }
}

// D) per-bucket final scatter: all writes land in one bucket's 35KB window (one XCD)
__global__ void finalscatter_kernel(const unsigned int* __restrict__ pk,
                                    const int* __restrict__ bb,
                                    int* __restrict__ cur, int* __restrict__ csrc) {
    int b = blockIdx.x;
    int beg = bb[b], end = bb[b + 1];
    int base = b << 9;
    for (int i = beg + threadIdx.x; i < end; i += blockDim.x) {
        unsigned int p = pk[i];
        int d = base + (int)(p >> 23);
        int s = (int)(p & 0x7FFFFFu);
        int slot = atomicAdd(&cur[d], 1);
        csrc[slot] = s;
    }
}

// ---- hierarchical per-node scan: A) per-block sums ----
__global__ void blocksum_kernel(const int* __restrict__ cnt, int* __restrict__ bsum, int n) {
    __shared__ int sdata[256];
    int i = blockIdx.x * 256 + threadIdx.x;
    sdata[threadIdx.x] = (i < n) ? cnt[i] : 0;
    __syncthreads();
    for (int off = 128; off; off >>= 1) {
        if (threadIdx.x < off) sdata[threadIdx.x] += sdata[threadIdx.x + off];
        __syncthreads();
    }
    if (threadIdx.x == 0) bsum[blockIdx.x] = sdata[0];
}

// ---- B) single-block exclusive scan of block sums (nb <= 1024) ----
__global__ void bscan_kernel(int* __restrict__ bsum, int nb) {
    __shared__ int sdata[1024];
    int t = threadIdx.x;
    int v = (t < nb) ? bsum[t] : 0;
    sdata[t] = v;
    __syncthreads();
    for (int off = 1; off < 1024; off <<= 1) {
        int u = (t >= off) ? sdata[t - off] : 0;
        __syncthreads();
        sdata[t] += u;
        __syncthreads();
    }
    if (t < nb) bsum[t] = sdata[t] - v;  // exclusive
}

// ---- C) per-block local scan + offset -> row, cur ----
__global__ void localscan_kernel(const int* __restrict__ cnt, const int* __restrict__ bsum,
                                 int* __restrict__ row, int* __restrict__ cur, int n) {
    __shared__ int sdata[256];
    int i = blockIdx.x * 256 + threadIdx.x;
    int v = (i < n) ? cnt[i] : 0;
    sdata[threadIdx.x] = v;
    __syncthreads();
    for (int off = 1; off < 256; off <<= 1) {
        int u = (threadIdx.x >= off) ? sdata[threadIdx.x - off] : 0;
        __syncthreads();
        sdata[threadIdx.x] += u;
        __syncthreads();
    }
    if (i < n) {
        int excl = bsum[blockIdx.x] + sdata[threadIdx.x] - v;
        row[i] = excl;
        cur[i] = excl;
        if (i == n - 1) row[n] = excl + v;
    }
}

// ================= GAT layers =================
template<int F_IN, int C_OUT, bool RELU_IN>
__global__ void gat_transform_kernel(const float* __restrict__ in,
                                     const float* __restrict__ W,
                                     const float* __restrict__ a_src,
                                     const float* __restrict__ a_dst,
                                     float* __restrict__ h,
                                     float* __restrict__ as,
                                     float* __restrict__ ad, int n) {
    __shared__ float sW[F_IN * C_OUT];
    __shared__ float sAs[C_OUT];
    __shared__ float sAd[C_OUT];
    for (int i = threadIdx.x; i < F_IN * C_OUT; i += blockDim.x) sW[i] = W[i];
    for (int i = threadIdx.x; i < C_OUT; i += blockDim.x) { sAs[i] = a_src[i]; sAd[i] = a_dst[i]; }
    __syncthreads();
    int i = blockIdx.x * blockDim.x + threadIdx.x;
    if (i >= n) return;
    float xin[F_IN];
#pragma unroll
    for (int f = 0; f < F_IN; ++f) {
        float v = in[(size_t)i * F_IN + f];
        if (RELU_IN) v = fmaxf(v, 0.f);
        xin[f] = v;
    }
    float s_acc = 0.f, d_acc = 0.f;
#pragma unroll
    for (int c = 0; c < C_OUT; ++c) {
        float acc = 0.f;
#pragma unroll
        for (int f = 0; f < F_IN; ++f) acc = fmaf(xin[f], sW[f * C_OUT + c], acc);
        h[(size_t)i * C_OUT + c] = acc;
        s_acc = fmaf(acc, sAs[c], s_acc);
        d_acc = fmaf(acc, sAd[c], d_acc);
    }
    as[i] = s_acc;
    ad[i] = d_acc;
}

// fused per-node softmax + aggregate: one WAVE per node
template<int C>
__global__ void gat_node_agg_kernel(const int* __restrict__ row,
                                    const int* __restrict__ csrc,
                                    const float* __restrict__ as,
                                    const float* __restrict__ ad,
                                    const float* __restrict__ h,
                                    const float* __restrict__ b,
                                    float* __restrict__ X, int n) {
    constexpr int LPR = C / 4;     // lanes per h-row
    constexpr int EPW = 64 / LPR;  // edges in flight
    int node = (blockIdx.x * blockDim.x + threadIdx.x) >> 6;
    int lane = threadIdx.x & 63;
    if (node >= n) return;
    int beg = row[node], end = row[node + 1];
    float add = ad[node];

    float m = -3.0e38f, s = 0.f;
    for (int i = beg + lane; i < end; i += 64) {
        float v = lrelu(as[csrc[i]] + add);
        if (v > m) { s *= __expf(m - v); m = v; }
        s += __expf(v - m);
    }
#pragma unroll
    for (int k = 1; k < 64; k <<= 1) {
        float mo = __shfl_xor(m, k, 64);
        float so = __shfl_xor(s, k, 64);
        float M = fmaxf(m, mo);
        s = s * __expf(m - M) + so * __expf(mo - M);
        m = M;
    }
    float inv = 1.f / s;

    int eq = lane / LPR;
    int cl = lane % LPR;
    float4 acc = {0.f, 0.f, 0.f, 0.f};
    for (int i = beg; i < end; i += EPW) {
        int e = i + eq;
        if (e < end) {
            int src = csrc[e];
            float w = __expf(lrelu(as[src] + add) - m) * inv;
            const float4 hv = *reinterpret_cast<const float4*>(&h[(size_t)src * C + cl * 4]);
            acc.x = fmaf(w, hv.x, acc.x);
            acc.y = fmaf(w, hv.y, acc.y);
            acc.z = fmaf(w, hv.z, acc.z);
            acc.w = fmaf(w, hv.w, acc.w);
        }
    }
#pragma unroll
    for (int k = LPR; k < 64; k <<= 1) {
        acc.x += __shfl_xor(acc.x, k, 64);
        acc.y += __shfl_xor(acc.y, k, 64);
        acc.z += __shfl_xor(acc.z, k, 64);
        acc.w += __shfl_xor(acc.w, k, 64);
    }
    if (eq == 0) {
        const float4 bb = *reinterpret_cast<const float4*>(&b[cl * 4]);
        float4 o = {acc.x + bb.x, acc.y + bb.y, acc.z + bb.z, acc.w + bb.w};
        *reinterpret_cast<float4*>(&X[(size_t)node * C + cl * 4]) = o;
    }
}

// final linear 64 -> 10
__global__ void gat_linear_kernel(const float* __restrict__ X,
                                  const float* __restrict__ Wl,
                                  const float* __restrict__ bl,
                                  float* __restrict__ out, int n) {
    __shared__ float sW[64 * 10];
    __shared__ float sb[10];
    for (int i = threadIdx.x; i < 64 * 10; i += blockDim.x) sW[i] = Wl[i];
    for (int i = threadIdx.x; i < 10; i += blockDim.x) sb[i] = bl[i];
    __syncthreads();
    int i = blockIdx.x * blockDim.x + threadIdx.x;
    if (i >= n) return;
    float xin[64];
#pragma unroll
    for (int c = 0; c < 64; ++c) xin[c] = X[(size_t)i * 64 + c];
#pragma unroll
    for (int k = 0; k < 10; ++k) {
        float acc = sb[k];
#pragma unroll
        for (int c = 0; c < 64; ++c) acc = fmaf(xin[c], sW[c * 10 + k], acc);
        out[(size_t)i * 10 + k] = acc;
    }
}

extern "C" void kernel_launch(void* const* d_in, const int* in_sizes, int n_in,
                              void* d_out, int out_size, void* d_ws, size_t ws_size,
                              hipStream_t stream) {
    const float* x       = (const float*)d_in[0];
    const int*   ei      = (const int*)d_in[1];
    // d_in[2] = batch (unused)
    const float* W1      = (const float*)d_in[3];
    const float* a1_src  = (const float*)d_in[4];
    const float* a1_dst  = (const float*)d_in[5];
    const float* b1      = (const float*)d_in[6];
    const float* W2      = (const float*)d_in[7];
    const float* a2_src  = (const float*)d_in[8];
    const float* a2_dst  = (const float*)d_in[9];
    const float* b2      = (const float*)d_in[10];
    const float* Wl      = (const float*)d_in[11];
    const float* bl      = (const float*)d_in[12];
    float* out = (float*)d_out;

    const int N = in_sizes[2];        // 50000
    const int E = in_sizes[1] / 2;    // 800000
    const int ET = E + N;             // with self-loops

    char* ws = (char*)d_ws;
    size_t off = 0;
    auto alloc = [&](size_t bytes) {
        char* p = ws + off;
        off = (off + bytes + 255) & ~(size_t)255;
        return p;
    };
    float*        h    = (float*)alloc((size_t)N * 64 * 4);
    float*        X1   = (float*)alloc((size_t)N * 16 * 4);
    float*        X2   = (float*)alloc((size_t)N * 64 * 4);
    float*        as   = (float*)alloc((size_t)N * 4);
    float*        ad   = (float*)alloc((size_t)N * 4);
    int*          row  = (int*)alloc((size_t)(N + 1) * 4);
    int*          cnt  = (int*)alloc((size_t)N * 4);
    int*          cur  = (int*)alloc((size_t)N * 4);
    int*          csrc = (int*)alloc((size_t)ET * 4);
    unsigned int* pk   = (unsigned int*)alloc((size_t)ET * 4);
    int*          bsum = (int*)alloc((size_t)1024 * 4);
    (void)ws_size;

    const int B = 256;
    auto cdiv = [](int a, int b) { return (a + b - 1) / b; };

    const int NBUCK = cdiv(N, 512);          // 98 buckets of 512 nodes
    const int NBLK  = 256;                   // bin blocks
    const int CHB   = cdiv(ET, NBLK);        // edges per bin block
    int* bh = (int*)alloc((size_t)NBUCK * NBLK * 4);
    int* bb = (int*)alloc((size_t)(NBUCK + 1) * 4);
    const int NB = cdiv(N, 256);             // per-node scan blocks

    // ===== CSR build (bucketed two-level scatter) =====
    zero_cnt_kernel<<<cdiv(N, B), B, 0, stream>>>(cnt, N);
    bincount_kernel<<<NBLK, B, 0, stream>>>(ei, E, N, CHB, bh, cnt, NBUCK, NBLK);
    bhscan_kernel<<<1, 1024, 0, stream>>>(bh, bb, NBUCK * NBLK, NBUCK, NBLK);
    blocksum_kernel<<<NB, 256, 0, stream>>>(cnt, bsum, N);
    bscan_kernel<<<1, 1024, 0, stream>>>(bsum, NB);
    localscan_kernel<<<NB, 256, 0, stream>>>(cnt, bsum, row, cur, N);
    binscatter_kernel<<<NBLK, B, 0, stream>>>(ei, E, N, CHB, bh, pk, NBUCK, NBLK);
    finalscatter_kernel<<<NBUCK, 512, 0, stream>>>(pk, bb, cur, csrc);

    // ===== layer 1 (11 -> 16) =====
    gat_transform_kernel<11, 16, false><<<cdiv(N, B), B, 0, stream>>>(x, W1, a1_src, a1_dst, h, as, ad, N);
    gat_node_agg_kernel<16><<<cdiv(N * 64, B), B, 0, stream>>>(row, csrc, as, ad, h, b1, X1, N);

    // ===== layer 2 (16 -> 64), input relu(X1) =====
    gat_transform_kernel<16, 64, true><<<cdiv(N, B), B, 0, stream>>>(X1, W2, a2_src, a2_dst, h, as, ad, N);
    gat_node_agg_kernel<64><<<cdiv(N * 64, B), B, 0, stream>>>(row, csrc, as, ad, h, b2, X2, N);

    // ===== final linear (64 -> 10) =====
    gat_linear_kernel<<<cdiv(N, B), B, 0, stream>>>(X2, Wl, bl, out, N);
}